// Round 4
// baseline (419.210 us; speedup 1.0000x reference)
//
#include <hip/hip_runtime.h>

// DiscriminativeLoss — B=8, D=32, N=131072, K=64 bins.
// R4 A/B experiment: R3 showed k1 at 180us even with x fully L3-resident
// (FETCH=4.3MB, dur unchanged) and zero global atomics -> bandwidth AND
// atomics exonerated. Invariant suspect: per-thread 32-stream walk at exact
// 512KB stride (L1/L2 set camping). This round:
//   k0: pack ids to 1B/pt + per-(b,k) counts (LDS int histogram)
//   k1: RESTRUCTURED - block owns (b, 4 d-rows, 16K-pt span): 4 contiguous
//       64KB streams, wave-private LDS bins, plain-store partials
//   k2: reduce partials -> mu
//   k3: CONTROL - R3 structure unchanged (32-stream strided walk)
//   k4: finalize
// If k1 << k3 next round: stride theory confirmed, restructure k3 the same way.

#define IGNORE_IDX (-100)

constexpr int B = 8;
constexpr int D = 32;
constexpr int K = 64;
constexpr int RPG  = 4;                // x-rows per k1 block
constexpr int DG   = D / RPG;          // 8 d-groups
constexpr int SP   = 8;                // spans per batch (k1)
constexpr int SPAN = 16384;            // pts per k1 block (N/SP)
constexpr int CH   = 64;               // chunks per batch (k3), 2048 pts each
constexpr float DELTA_V = 0.5f;
constexpr float TWO_DELTA_D = 3.0f;    // 2 * DELTA_D
constexpr float PARAM_REG = 0.001f;

// ws float layout:
//   part : [B][DG][SP][RPG*K] = 131072 @ 0
//   mu   : [B][K][D]          = 16384  @ OFF_MU
//   vpart: [B][CH][K]         = 32768  @ OFF_VP
//   cnt  : [B][K] (int)       = 512    @ OFF_CNT
//   id8  : [B][N] (uchar)     = 262144 float-slots @ OFF_ID
constexpr int OFF_MU  = B * DG * SP * RPG * K;
constexpr int OFF_VP  = OFF_MU + B * K * D;
constexpr int OFF_CNT = OFF_VP + B * CH * K;
constexpr int OFF_ID  = OFF_CNT + B * K;

// ---------------------------------------------------------------- K0: ids + counts
__global__ __launch_bounds__(256) void k0_ids(
    const int* __restrict__ sem, const int* __restrict__ inst,
    unsigned char* __restrict__ id8, int* __restrict__ cnt, int N)
{
    __shared__ int s_cnt[K];
    const int t = threadIdx.x;
    const int b = blockIdx.x / (N / 2048);
    if (t < K) s_cnt[t] = 0;
    __syncthreads();

    const int base = blockIdx.x * 2048 + t * 8;   // global point index
    const int4 c0 = *(const int4*)(sem + base);
    const int4 c1 = *(const int4*)(sem + base + 4);
    const int4 i0 = *(const int4*)(inst + base);
    const int4 i1 = *(const int4*)(inst + base + 4);
    const int cl[8] = {c0.x, c0.y, c0.z, c0.w, c1.x, c1.y, c1.z, c1.w};
    const int il[8] = {i0.x, i0.y, i0.z, i0.w, i1.x, i1.y, i1.z, i1.w};

    unsigned int w0 = 0, w1 = 0;
#pragma unroll
    for (int j = 0; j < 8; ++j) {
        const bool v = (cl[j] != IGNORE_IDX);
        int q = (cl[j] == 1) ? 0 : il[j];
        q = (q < 0) ? 0 : (q > K - 1 ? K - 1 : q);
        if (v) atomicAdd(&s_cnt[q], 1);
        const unsigned byte = v ? (unsigned)q : 255u;
        if (j < 4) w0 |= byte << (8 * j);
        else       w1 |= byte << (8 * (j - 4));
    }
    *(uint2*)(id8 + base) = make_uint2(w0, w1);
    __syncthreads();

    if (t < K) {
        const int c = s_cnt[t];
        if (c) atomicAdd(&cnt[b * K + t], c);
    }
}

// ---------------------------------------------------------------- K1: contiguous-stream partial sums
__global__ __launch_bounds__(256) void k1_segsum(
    const float* __restrict__ x, const unsigned char* __restrict__ id8,
    float* __restrict__ part, int N)
{
    __shared__ float s_acc[4][RPG][K];   // wave-private bins, 4KB
    const int t = threadIdx.x;
    const int w = t >> 6;
    const int blk = blockIdx.x;          // = ((b*DG)+dg)*SP + sp
    const int sp  = blk & (SP - 1);
    const int dg  = (blk / SP) & (DG - 1);
    const int b   = blk / (SP * DG);

    for (int i = t; i < 4 * RPG * K; i += 256) ((float*)s_acc)[i] = 0.f;
    __syncthreads();

    const float* xb = x + (size_t)b * D * N + (size_t)(dg * RPG) * N + sp * SPAN;
    const unsigned char* idb = id8 + (size_t)b * N + sp * SPAN;

    for (int it = 0; it < SPAN / 1024; ++it) {   // 16 iters, 4 pts/thread each
        const int base = it * 1024 + t * 4;
        const unsigned idw = *(const unsigned*)(idb + base);
        float xv[RPG][4];
#pragma unroll
        for (int r = 0; r < RPG; ++r) {
            const float4 f = *(const float4*)(xb + (size_t)r * N + base);
            xv[r][0] = f.x; xv[r][1] = f.y; xv[r][2] = f.z; xv[r][3] = f.w;
        }
#pragma unroll
        for (int j = 0; j < 4; ++j) {
            const unsigned id = (idw >> (8 * j)) & 255u;
            if (id < 64u) {
#pragma unroll
                for (int r = 0; r < RPG; ++r)
                    unsafeAtomicAdd(&s_acc[w][r][id], xv[r][j]);
            }
        }
    }
    __syncthreads();

    float* dst = part + (size_t)blk * (RPG * K);
    for (int i = t; i < RPG * K; i += 256) {     // 256 cells, one per thread
        dst[i] = ((float*)s_acc)[0 * 256 + i] + ((float*)s_acc)[1 * 256 + i]
               + ((float*)s_acc)[2 * 256 + i] + ((float*)s_acc)[3 * 256 + i];
    }
}

// ---------------------------------------------------------------- K2: reduce -> mu
__global__ __launch_bounds__(256) void k2_mu(const float* __restrict__ part,
                                             const int* __restrict__ cnt,
                                             float* __restrict__ mu)
{
    const int gid  = blockIdx.x * 256 + threadIdx.x;  // B*K*D = 16384
    const int b    = gid >> 11;
    const int cell = gid & 2047;
    const int k = cell >> 5, d = cell & 31;
    const int dg = d >> 2, r = d & 3;

    float s = 0.f;
#pragma unroll
    for (int sp = 0; sp < SP; ++sp)
        s += part[(size_t)(((b * DG + dg) * SP) + sp) * (RPG * K) + r * K + k];
    const float c = (float)cnt[b * K + k];
    mu[b * K * D + k * D + d] = s / (c + 1e-8f);
}

// ---------------------------------------------------------------- K3: variance pass (CONTROL: R3 structure)
__global__ __launch_bounds__(256) void k3_var(
    const float* __restrict__ x, const unsigned char* __restrict__ id8,
    const float* __restrict__ mu, float* __restrict__ vpart, int N)
{
    __shared__ float s_mu[K][D + 1];
    __shared__ float s_var[K];

    const int b     = blockIdx.x >> 6;
    const int chunk = blockIdx.x & 63;
    const int t     = threadIdx.x;

    for (int i = t; i < K * D; i += 256) s_mu[i >> 5][i & 31] = mu[b * K * D + i];
    if (t < K) s_var[t] = 0.f;
    __syncthreads();

    const float* xb = x + (size_t)b * D * N;
    const unsigned char* idb = id8 + (size_t)b * N;

#pragma unroll
    for (int g = 0; g < 2; ++g) {
        const int base = chunk * 2048 + g * 1024 + t * 4;
        const unsigned idw = *(const unsigned*)(idb + base);
        int  id[4];
        bool v[4];
#pragma unroll
        for (int j = 0; j < 4; ++j) {
            const unsigned q = (idw >> (8 * j)) & 255u;
            v[j]  = (q < 64u);
            id[j] = v[j] ? (int)q : 0;
        }
        float dist[4] = {0.f, 0.f, 0.f, 0.f};
#pragma unroll
        for (int dc = 0; dc < 4; ++dc) {
            float4 xv[8];
#pragma unroll
            for (int dd = 0; dd < 8; ++dd)
                xv[dd] = *(const float4*)(xb + (size_t)(dc * 8 + dd) * N + base);
#pragma unroll
            for (int dd = 0; dd < 8; ++dd) {
                const int d = dc * 8 + dd;
                dist[0] += fabsf(xv[dd].x - s_mu[id[0]][d]);
                dist[1] += fabsf(xv[dd].y - s_mu[id[1]][d]);
                dist[2] += fabsf(xv[dd].z - s_mu[id[2]][d]);
                dist[3] += fabsf(xv[dd].w - s_mu[id[3]][d]);
            }
        }
#pragma unroll
        for (int j = 0; j < 4; ++j) {
            if (v[j]) {
                const float h = fmaxf(dist[j] - DELTA_V, 0.f);
                if (h > 0.f) unsafeAtomicAdd(&s_var[id[j]], h * h);
            }
        }
    }
    __syncthreads();

    if (t < K) vpart[((size_t)b * CH + chunk) * K + t] = s_var[t];
}

// ---------------------------------------------------------------- K4: finalize (1 block)
__device__ float block_reduce_sum512(float v, float* s_buf) {
    for (int o = 32; o > 0; o >>= 1) v += __shfl_down(v, o, 64);
    const int wid  = threadIdx.x >> 6;
    const int lane = threadIdx.x & 63;
    if (lane == 0) s_buf[wid] = v;
    __syncthreads();
    float r = 0.f;
    if (threadIdx.x == 0)
        for (int w = 0; w < 8; ++w) r += s_buf[w];
    __syncthreads();
    return r;
}

__global__ __launch_bounds__(512) void k4_final(const float* __restrict__ mu,
                                                const int* __restrict__ cnt,
                                                const float* __restrict__ vpart,
                                                float* __restrict__ out)
{
    __shared__ float s_mu[K][D + 1];
    __shared__ float s_cnt[B * K];
    __shared__ float s_varseg[B * K];
    __shared__ float s_red[8];

    const int t = threadIdx.x;

    s_cnt[t] = (float)cnt[t];            // 512 == B*K
    __syncthreads();

    {
        const int b = t >> 6, k = t & 63;
        float vs = 0.f;
        for (int ch = 0; ch < CH; ++ch)
            vs += vpart[((size_t)b * CH + ch) * K + k];
        s_varseg[t] = vs / (s_cnt[t] + 1e-8f);
    }
    __syncthreads();

    float acc_loss = 0.f, acc_var = 0.f, acc_dist = 0.f, acc_reg = 0.f;

    for (int b = 0; b < B; ++b) {
        for (int i = t; i < K * D; i += 512) s_mu[(i >> 5)][i & 31] = mu[b * K * D + i];
        __syncthreads();

        float distPart = 0.f;
        for (int p = t; p < K * K; p += 512) {
            const int i = p >> 6, j = p & 63;
            if (i != j && s_cnt[b * K + i] > 0.f && s_cnt[b * K + j] > 0.f) {
                float dsum = 0.f;
#pragma unroll
                for (int d = 0; d < D; ++d) dsum += fabsf(s_mu[i][d] - s_mu[j][d]);
                const float h = fmaxf(TWO_DELTA_D - dsum, 0.f);
                distPart += h * h;
            }
        }
        float regPart = 0.f;
        for (int i = t; i < K * D; i += 512) {
            const int k = i >> 5;
            if (s_cnt[b * K + k] > 0.f) regPart += fabsf(s_mu[k][i & 31]);
        }

        const float distSum = block_reduce_sum512(distPart, s_red);
        const float regSum  = block_reduce_sum512(regPart,  s_red);

        if (t == 0) {
            float np = 0.f, varSum = 0.f;
            for (int k = 0; k < K; ++k) {
                np     += (s_cnt[b * K + k] > 0.f) ? 1.f : 0.f;
                varSum += s_varseg[b * K + k];
            }
            const float n_inst = fmaxf(np, 1.0f);
            const float npairs = np * np - np;
            const float l_var  = varSum / n_inst;
            const float l_dist = (npairs > 0.f) ? (distSum / fmaxf(npairs, 1.0f)) : 0.f;
            const float l_reg  = PARAM_REG * (regSum / n_inst);
            acc_loss += l_var + l_dist + l_reg;
            acc_var  += l_var;
            acc_dist += l_dist;
            acc_reg  += l_reg;
        }
        __syncthreads();
    }

    if (t == 0) {
        const float invB = 1.0f / (float)B;
        out[0] = acc_loss * invB;
        out[1] = acc_var  * invB;
        out[2] = acc_dist * invB;
        out[3] = acc_reg  * invB;
    }
}

// ---------------------------------------------------------------- launch
extern "C" void kernel_launch(void* const* d_in, const int* in_sizes, int n_in,
                              void* d_out, int out_size, void* d_ws, size_t ws_size,
                              hipStream_t stream) {
    const float* x    = (const float*)d_in[0];
    const int*   sem  = (const int*)d_in[1];
    const int*   inst = (const int*)d_in[2];
    float*       out  = (float*)d_out;
    float*       ws   = (float*)d_ws;

    float*         part  = ws;
    float*         mu    = ws + OFF_MU;
    float*         vpart = ws + OFF_VP;
    int*           cnt   = (int*)(ws + OFF_CNT);
    unsigned char* id8   = (unsigned char*)(ws + OFF_ID);

    const int N = in_sizes[1] / B;

    hipMemsetAsync(cnt, 0, B * K * sizeof(int), stream);

    k0_ids<<<dim3(B * N / 2048), dim3(256), 0, stream>>>(sem, inst, id8, cnt, N);
    k1_segsum<<<dim3(B * DG * SP), dim3(256), 0, stream>>>(x, id8, part, N);
    k2_mu<<<dim3(B * K * D / 256), dim3(256), 0, stream>>>(part, cnt, mu);
    k3_var<<<dim3(B * CH), dim3(256), 0, stream>>>(x, id8, mu, vpart, N);
    k4_final<<<dim3(1), dim3(512), 0, stream>>>(mu, cnt, vpart, out);
}